// Round 13
// baseline (931.679 us; speedup 1.0000x reference)
//
#include <hip/hip_runtime.h>
#include <hip/hip_bf16.h>
#include <math.h>

typedef unsigned short u16;
typedef unsigned int   u32;
typedef __attribute__((ext_vector_type(8))) short bf16x8;   // 8 bf16 = 4 VGPR
typedef __attribute__((ext_vector_type(4))) float f32x4;

__device__ __forceinline__ u16 f2bf(float f){
  u32 u = __float_as_uint(f);
  u += 0x7fffu + ((u>>16)&1u);          // RNE; inputs never NaN
  return (u16)(u>>16);
}
__device__ __forceinline__ u32 pack2(float a, float b){
  return (u32)f2bf(a) | ((u32)f2bf(b)<<16);
}
__device__ __forceinline__ float bf2f(u16 u){ return __uint_as_float(((u32)u)<<16); }
__device__ __forceinline__ float2 LDF2(const float* p){ return *(const float2*)p; }
__device__ __forceinline__ float gelu_f(float v){
  float t = __expf(1.5957691216057308f * fmaf(0.044715f*v, v*v, v));
  return v - v*__builtin_amdgcn_rcpf(t + 1.0f);   // tanh-form GELU, fast rcp
}

#define ST_U32(p,v) (*(u32*)(p) = (v))
#define LD_U32(p)   (*(const u32*)(p))
#define MFMA16(a,b,c) __builtin_amdgcn_mfma_f32_16x16x32_bf16((a),(b),(c),0,0,0)

__device__ __forceinline__ bf16x8 ldsfrag(const u16* p){ return *(const bf16x8*)p; }
__device__ __forceinline__ bf16x8 gfrag(const u16* p){ return *(const bf16x8*)p; }

constexpr float SCALE_Q = 0.17677669529663687f;  // 32^-0.5
constexpr float LN_EPS  = 1e-5f;

// ws element counts (u16)
#define NQKV 110592
#define NPRJ 36864
#define NFC  147456
#define QKV_SLAB 50331648ull        // 4096*64*192 u16 per slab (Q/K/VT/x1b)
#define WS_WEIGHTS_B 884736ull
#define WS_RPBM_B    98304ull
#define WS_SPLIT_HDR (WS_WEIGHTS_B + 2*WS_RPBM_B)             // 1081344 B
#define WS_SPLIT_NEED  (WS_SPLIT_HDR + 3ull*QKV_SLAB*2ull)    // ~303 MB
#define WS_SPLIT2_NEED (WS_SPLIT_HDR + 4ull*QKV_SLAB*2ull)    // ~404 MB (r9: available)

// =====================================================================
// K0: weight f32->bf16 conversion + rpb gather (row-major, + transposed)
// =====================================================================
__global__ void k_prep(const float* __restrict__ qkv_w, const float* __restrict__ proj_w,
                       const float* __restrict__ fc1_w, const float* __restrict__ fc2_w,
                       const float* __restrict__ rpb, const int* __restrict__ relidx,
                       u16* __restrict__ qkv_bf, u16* __restrict__ proj_bf,
                       u16* __restrict__ fc1_bf, u16* __restrict__ fc2_bf,
                       float* __restrict__ rpbm, float* __restrict__ rpbmT, int mode)
{
  int stride = gridDim.x * blockDim.x;
  int t = blockIdx.x * blockDim.x + threadIdx.x;
  for (int i = t; i < NQKV; i += stride) qkv_bf[i] = f2bf(qkv_w[i]);
  for (int i = t; i < NPRJ; i += stride) proj_bf[i] = f2bf(proj_w[i]);
  for (int i = t; i < NFC;  i += stride) fc1_bf[i]  = f2bf(fc1_w[i]);
  for (int i = t; i < NFC;  i += stride) fc2_bf[i]  = f2bf(fc2_w[i]);
  for (int i = t; i < 6*4096; i += stride){
    int h = i >> 12, ij = i & 4095;
    rpbm[i] = rpb[relidx[ij]*6 + h];
  }
  if (mode){
    for (int i = t; i < 6*4096; i += stride){
      int h = i >> 12, ij = i & 4095;           // ij = col*64 + row (transposed)
      int col = ij >> 6, row = ij & 63;
      rpbmT[i] = rpb[relidx[row*64 + col]*6 + h];
    }
  }
}

// =====================================================================
// K1a (split): per-window qkv GEMM -> Qg (scaled), Kg, VTg (transposed)
// =====================================================================
__global__ __launch_bounds__(256, 4) void k_qkv(
    const float* __restrict__ x, const u16* __restrict__ qkv_bf,
    const float* __restrict__ qkv_b,
    u16* __restrict__ Qg, u16* __restrict__ Kg, u16* __restrict__ VTg)
{
  __shared__ __align__(16) u16 xw[64*200];
  const int tid = threadIdx.x, wave = tid >> 6, lane = tid & 63;
  const int kg = lane >> 4, l15 = lane & 15;
  const int wi = blockIdx.x, b = wi >> 10, wm = wi & 1023;
  const int wh = wm >> 5, ww = wm & 31;
  const size_t imgbase = (size_t)b * (256*256*192);

  for (int s = tid; s < 64*96; s += 256){
    int t = s / 96, c2 = s - t*96;
    int i = t >> 3, j = t & 7;
    int h0 = ((wh<<3) + i + 4) & 255;
    int w0 = ((ww<<3) + j + 4) & 255;
    float2 v = LDF2(x + imgbase + (size_t)(h0*256 + w0)*192 + c2*2);
    ST_U32(xw + t*200 + c2*2, pack2(v.x, v.y));
  }
  __syncthreads();

  const size_t wbase = (size_t)wi * 12288;
  #pragma unroll 1
  for (int batch = 0; batch < 3; ++batch){
    const int col0 = wave*144 + batch*48;
    f32x4 a[4][3];
    #pragma unroll
    for (int j = 0; j < 3; ++j){
      float bv = qkv_b[col0 + j*16 + l15];
      #pragma unroll
      for (int mt = 0; mt < 4; ++mt) a[mt][j] = {bv, bv, bv, bv};
    }
    #pragma unroll 2
    for (int kt = 0; kt < 6; ++kt){
      bf16x8 af[4];
      #pragma unroll
      for (int mt = 0; mt < 4; ++mt)
        af[mt] = ldsfrag(xw + (mt*16 + l15)*200 + kt*32 + kg*8);
      #pragma unroll
      for (int j = 0; j < 3; ++j){
        bf16x8 bfr = gfrag(qkv_bf + (col0 + j*16 + l15)*192 + kt*32 + kg*8);
        #pragma unroll
        for (int mt = 0; mt < 4; ++mt)
          a[mt][j] = MFMA16(af[mt], bfr, a[mt][j]);
      }
    }
    #pragma unroll
    for (int j = 0; j < 3; ++j){
      int colg = col0 + j*16 + l15;          // uniform section per (wave,batch,j)
      if (colg < 192){
        #pragma unroll
        for (int mt = 0; mt < 4; ++mt)
          #pragma unroll
          for (int r = 0; r < 4; ++r)
            Qg[wbase + (size_t)(mt*16 + kg*4 + r)*192 + colg] = f2bf(a[mt][j][r]*SCALE_Q);
      } else if (colg < 384){
        #pragma unroll
        for (int mt = 0; mt < 4; ++mt)
          #pragma unroll
          for (int r = 0; r < 4; ++r)
            Kg[wbase + (size_t)(mt*16 + kg*4 + r)*192 + (colg - 192)] = f2bf(a[mt][j][r]);
      } else {
        #pragma unroll
        for (int mt = 0; mt < 4; ++mt){
          ushort4 pk = { f2bf(a[mt][j][0]), f2bf(a[mt][j][1]),
                         f2bf(a[mt][j][2]), f2bf(a[mt][j][3]) };
          *(ushort4*)(VTg + wbase + (size_t)(colg - 384)*64 + mt*16 + kg*4) = pk;
        }
      }
    }
  }
}

// =====================================================================
// K1b (split): attention core + proj + LN1 + residual
// writes x1 (f32) if non-null, x1b (bf16) if non-null.
// mask skipped for interior windows (only wh==31 or ww==31 have mask!=0)
// =====================================================================
__global__ __launch_bounds__(256, 4) void k_attn2(
    const float* __restrict__ x, const float* __restrict__ mask,
    const float* __restrict__ rpbmT,
    const u16* __restrict__ Qg, const u16* __restrict__ Kg,
    const u16* __restrict__ VTg,
    const u16* __restrict__ proj_bf, const float* __restrict__ proj_b,
    const float* __restrict__ n1g, const float* __restrict__ n1b,
    float* __restrict__ x1, u16* __restrict__ x1b)
{
  __shared__ __align__(16) u16 prb[64*72];
  __shared__ __align__(16) u16 obuf[64*200];
  __shared__ float lnred[64*8];

  const int tid = threadIdx.x, wave = tid >> 6, lane = tid & 63;
  const int kg = lane >> 4, l15 = lane & 15;
  const int wi = blockIdx.x, b = wi >> 10, wm = wi & 1023;
  const int wh = wm >> 5, ww = wm & 31;
  const bool hasmask = (wh == 31) || (ww == 31);
  const size_t imgbase = (size_t)b * (256*256*192);
  const size_t wbase = (size_t)wi * 12288;

  f32x4 pj[4][3];
  #pragma unroll
  for (int mt = 0; mt < 4; ++mt)
    #pragma unroll
    for (int nt = 0; nt < 3; ++nt){
      float bv = proj_b[wave*48 + nt*16 + l15];
      pj[mt][nt] = {bv, bv, bv, bv};
    }

  #pragma unroll 1
  for (int h = 0; h < 6; ++h){
    const f32x4 z = {0.f, 0.f, 0.f, 0.f};
    bf16x8 qf = gfrag(Qg + wbase + (size_t)(wave*16 + l15)*192 + h*32 + kg*8);
    f32x4 at[4];
    #pragma unroll
    for (int nt = 0; nt < 4; ++nt){
      bf16x8 kf = gfrag(Kg + wbase + (size_t)(nt*16 + l15)*192 + h*32 + kg*8);
      at[nt] = MFMA16(qf, kf, z);
    }
    {
      const float* rb = rpbmT + h*4096;
      #pragma unroll
      for (int nt = 0; nt < 4; ++nt){
        int cidx = (nt*16 + l15)*64 + wave*16 + kg*4;
        float4 r4 = *(const float4*)(rb + cidx);
        at[nt][0] += r4.x;
        at[nt][1] += r4.y;
        at[nt][2] += r4.z;
        at[nt][3] += r4.w;
      }
    }
    if (hasmask){
      const float* mb = mask + (size_t)wm*4096;
      #pragma unroll
      for (int nt = 0; nt < 4; ++nt){
        int cidx = (nt*16 + l15)*64 + wave*16 + kg*4;
        float4 m4 = *(const float4*)(mb + cidx);
        at[nt][0] += m4.x;
        at[nt][1] += m4.y;
        at[nt][2] += m4.z;
        at[nt][3] += m4.w;
      }
    }
    #pragma unroll
    for (int r = 0; r < 4; ++r){
      float m0 = fmaxf(fmaxf(at[0][r], at[1][r]), fmaxf(at[2][r], at[3][r]));
      #pragma unroll
      for (int mk = 1; mk < 16; mk <<= 1) m0 = fmaxf(m0, __shfl_xor(m0, mk));
      float s = 0.f;
      #pragma unroll
      for (int nt = 0; nt < 4; ++nt){ at[nt][r] = __expf(at[nt][r] - m0); s += at[nt][r]; }
      #pragma unroll
      for (int mk = 1; mk < 16; mk <<= 1) s += __shfl_xor(s, mk);
      float inv = __builtin_amdgcn_rcpf(s);
      #pragma unroll
      for (int nt = 0; nt < 4; ++nt) at[nt][r] *= inv;
    }
    #pragma unroll
    for (int nt = 0; nt < 4; ++nt)
      #pragma unroll
      for (int r = 0; r < 4; ++r)
        prb[(wave*16 + kg*4 + r)*72 + nt*16 + l15] = f2bf(at[nt][r]);
    // (prb rows wave-local; no barrier needed)
    {
      f32x4 ov[2] = {z, z};
      #pragma unroll
      for (int kt = 0; kt < 2; ++kt){
        bf16x8 pf = ldsfrag(prb + (wave*16 + l15)*72 + kt*32 + kg*8);
        #pragma unroll
        for (int d = 0; d < 2; ++d){
          bf16x8 vf = gfrag(VTg + wbase + (size_t)(h*32 + d*16 + l15)*64 + kt*32 + kg*8);
          ov[d] = MFMA16(pf, vf, ov[d]);
        }
      }
      #pragma unroll
      for (int d = 0; d < 2; ++d)
        #pragma unroll
        for (int r = 0; r < 4; ++r)
          obuf[(wave*16 + kg*4 + r)*200 + h*32 + d*16 + l15] = f2bf(ov[d][r]);
    }
  }
  __syncthreads();

  #pragma unroll 2
  for (int kt = 0; kt < 6; ++kt){
    bf16x8 af[4];
    #pragma unroll
    for (int mt = 0; mt < 4; ++mt)
      af[mt] = ldsfrag(obuf + (mt*16 + l15)*200 + kt*32 + kg*8);
    #pragma unroll
    for (int nt = 0; nt < 3; ++nt){
      bf16x8 bfr = gfrag(proj_bf + (wave*48 + nt*16 + l15)*192 + kt*32 + kg*8);
      #pragma unroll
      for (int mt = 0; mt < 4; ++mt)
        pj[mt][nt] = MFMA16(af[mt], bfr, pj[mt][nt]);
    }
  }

  float gv[3], bv2[3];
  #pragma unroll
  for (int nt = 0; nt < 3; ++nt){
    int c = wave*48 + nt*16 + l15;
    gv[nt] = n1g[c]; bv2[nt] = n1b[c];
  }
  #pragma unroll
  for (int mt = 0; mt < 4; ++mt)
    #pragma unroll
    for (int r = 0; r < 4; ++r){
      float s1 = pj[mt][0][r] + pj[mt][1][r] + pj[mt][2][r];
      float s2 = pj[mt][0][r]*pj[mt][0][r] + pj[mt][1][r]*pj[mt][1][r] + pj[mt][2][r]*pj[mt][2][r];
      #pragma unroll
      for (int mk = 1; mk < 16; mk <<= 1){ s1 += __shfl_xor(s1, mk); s2 += __shfl_xor(s2, mk); }
      if (l15 == 0){
        int t = mt*16 + kg*4 + r;
        lnred[t*8 + wave*2]     = s1;
        lnred[t*8 + wave*2 + 1] = s2;
      }
    }
  __syncthreads();
  const bool wf = (x1 != nullptr);
  const bool wb = (x1b != nullptr);
  #pragma unroll
  for (int mt = 0; mt < 4; ++mt)
    #pragma unroll 1
    for (int r = 0; r < 4; ++r){
      int t = mt*16 + kg*4 + r;
      float a1 = lnred[t*8+0] + lnred[t*8+2] + lnred[t*8+4] + lnred[t*8+6];
      float a2 = lnred[t*8+1] + lnred[t*8+3] + lnred[t*8+5] + lnred[t*8+7];
      float mu = a1 * (1.f/192.f);
      float rs = rsqrtf(a2 * (1.f/192.f) - mu*mu + LN_EPS);
      int i = t >> 3, j = t & 7;
      int h0 = ((wh<<3) + i + 4) & 255, w0 = ((ww<<3) + j + 4) & 255;
      size_t base = imgbase + (size_t)(h0*256 + w0)*192;
      #pragma unroll
      for (int nt = 0; nt < 3; ++nt){
        int c = wave*48 + nt*16 + l15;
        float y = x[base + c] + (pj[mt][nt][r] - mu)*rs*gv[nt] + bv2[nt];
        if (wf) x1[base + c] = y;
        if (wb) x1b[base + c] = f2bf(y);
      }
    }
}

// =====================================================================
// K1 (fallback): monolithic attention (round-4 proven)
// =====================================================================
__global__ __launch_bounds__(256, 3) void k_attn(
    const float* __restrict__ x, const float* __restrict__ mask,
    const float* __restrict__ rpbm, const u16* __restrict__ qkv_bf,
    const float* __restrict__ qkv_b, const u16* __restrict__ proj_bf,
    const float* __restrict__ proj_b, const float* __restrict__ n1g,
    const float* __restrict__ n1b, float* __restrict__ x1)
{
  __shared__ __align__(16) u16 xw[64*200];
  __shared__ __align__(16) u16 qkvh[64*72];
  __shared__ __align__(16) u16 vT[32*72];
  __shared__ __align__(16) u16 prb[64*72];
  __shared__ __align__(16) u16 outh[64*40];
  float* lnred = (float*)outh;

  const int tid  = threadIdx.x;
  const int wave = tid >> 6, lane = tid & 63;
  const int kg   = lane >> 4, l15 = lane & 15;
  const int wi = blockIdx.x;
  const int b  = wi >> 10, wm = wi & 1023;
  const int wh = wm >> 5,  ww = wm & 31;
  const size_t imgbase = (size_t)b * (256*256*192);

  for (int s = tid; s < 64*96; s += 256){
    int t = s / 96, c2 = s - t*96;
    int i = t >> 3, j = t & 7;
    int h0 = ((wh<<3) + i + 4) & 255;
    int w0 = ((ww<<3) + j + 4) & 255;
    float2 v = LDF2(x + imgbase + (size_t)(h0*256 + w0)*192 + c2*2);
    ST_U32(xw + t*200 + c2*2, pack2(v.x, v.y));
  }

  f32x4 pj[4][3];
  #pragma unroll
  for (int mt = 0; mt < 4; ++mt)
    #pragma unroll
    for (int nt = 0; nt < 3; ++nt){
      float bv = proj_b[wave*48 + nt*16 + l15];
      pj[mt][nt] = {bv, bv, bv, bv};
    }
  __syncthreads();

  #pragma unroll 1
  for (int h = 0; h < 6; ++h){
    f32x4 qa[6];
    #pragma unroll
    for (int nt = 0; nt < 6; ++nt){
      float bv = qkv_b[(nt>>1)*192 + h*32 + (nt&1)*16 + l15];
      qa[nt] = {bv, bv, bv, bv};
    }
    #pragma unroll 2
    for (int kt = 0; kt < 6; ++kt){
      bf16x8 af = ldsfrag(xw + (wave*16 + l15)*200 + kt*32 + kg*8);
      #pragma unroll
      for (int nt = 0; nt < 6; ++nt){
        bf16x8 bfr = gfrag(qkv_bf + ((nt>>1)*192 + h*32 + (nt&1)*16 + l15)*192 + kt*32 + kg*8);
        qa[nt] = MFMA16(af, bfr, qa[nt]);
      }
    }
    #pragma unroll
    for (int nt = 0; nt < 2; ++nt)
      #pragma unroll
      for (int r = 0; r < 4; ++r)
        qkvh[(wave*16 + kg*4 + r)*72 + nt*16 + l15] = f2bf(qa[nt][r]*SCALE_Q);
    #pragma unroll
    for (int nt = 2; nt < 4; ++nt)
      #pragma unroll
      for (int r = 0; r < 4; ++r)
        qkvh[(wave*16 + kg*4 + r)*72 + 32 + (nt-2)*16 + l15] = f2bf(qa[nt][r]);
    #pragma unroll
    for (int nt = 4; nt < 6; ++nt)
      #pragma unroll
      for (int r = 0; r < 4; ++r)
        vT[((nt-4)*16 + l15)*72 + wave*16 + kg*4 + r] = f2bf(qa[nt][r]);
    __syncthreads();

    f32x4 at[4];
    {
      const f32x4 z = {0.f, 0.f, 0.f, 0.f};
      bf16x8 qf = ldsfrag(qkvh + (wave*16 + l15)*72 + kg*8);
      #pragma unroll
      for (int nt = 0; nt < 4; ++nt){
        bf16x8 kf = ldsfrag(qkvh + (nt*16 + l15)*72 + 32 + kg*8);
        at[nt] = MFMA16(qf, kf, z);
      }
    }
    {
      const float* rb = rpbm + h*4096;
      const float* mb = mask + (size_t)wm*4096;
      #pragma unroll
      for (int nt = 0; nt < 4; ++nt)
        #pragma unroll
        for (int r = 0; r < 4; ++r){
          int idx = (wave*16 + kg*4 + r)*64 + nt*16 + l15;
          at[nt][r] += rb[idx] + mb[idx];
        }
    }
    #pragma unroll
    for (int r = 0; r < 4; ++r){
      float m0 = fmaxf(fmaxf(at[0][r], at[1][r]), fmaxf(at[2][r], at[3][r]));
      #pragma unroll
      for (int mk = 1; mk < 16; mk <<= 1) m0 = fmaxf(m0, __shfl_xor(m0, mk));
      float s = 0.f;
      #pragma unroll
      for (int nt = 0; nt < 4; ++nt){ at[nt][r] = __expf(at[nt][r] - m0); s += at[nt][r]; }
      #pragma unroll
      for (int mk = 1; mk < 16; mk <<= 1) s += __shfl_xor(s, mk);
      float inv = __builtin_amdgcn_rcpf(s);
      #pragma unroll
      for (int nt = 0; nt < 4; ++nt) at[nt][r] *= inv;
    }
    #pragma unroll
    for (int nt = 0; nt < 4; ++nt)
      #pragma unroll
      for (int r = 0; r < 4; ++r)
        prb[(wave*16 + kg*4 + r)*72 + nt*16 + l15] = f2bf(at[nt][r]);

    {
      f32x4 ov[2] = {{0,0,0,0},{0,0,0,0}};
      #pragma unroll
      for (int kt = 0; kt < 2; ++kt){
        bf16x8 pf = ldsfrag(prb + (wave*16 + l15)*72 + kt*32 + kg*8);
        #pragma unroll
        for (int nt = 0; nt < 2; ++nt){
          bf16x8 vf = ldsfrag(vT + (nt*16 + l15)*72 + kt*32 + kg*8);
          ov[nt] = MFMA16(pf, vf, ov[nt]);
        }
      }
      #pragma unroll
      for (int nt = 0; nt < 2; ++nt)
        #pragma unroll
        for (int r = 0; r < 4; ++r)
          outh[(wave*16 + kg*4 + r)*40 + nt*16 + l15] = f2bf(ov[nt][r]);
    }
    __syncthreads();

    {
      bf16x8 pw[3];
      #pragma unroll
      for (int nt = 0; nt < 3; ++nt)
        pw[nt] = gfrag(proj_bf + (wave*48 + nt*16 + l15)*192 + h*32 + kg*8);
      #pragma unroll
      for (int mt = 0; mt < 4; ++mt){
        bf16x8 af = ldsfrag(outh + (mt*16 + l15)*40 + kg*8);
        #pragma unroll
        for (int nt = 0; nt < 3; ++nt)
          pj[mt][nt] = MFMA16(af, pw[nt], pj[mt][nt]);
      }
    }
    __syncthreads();
  }

  float gv[3], bv2[3];
  #pragma unroll
  for (int nt = 0; nt < 3; ++nt){
    int c = wave*48 + nt*16 + l15;
    gv[nt] = n1g[c]; bv2[nt] = n1b[c];
  }
  #pragma unroll
  for (int mt = 0; mt < 4; ++mt)
    #pragma unroll
    for (int r = 0; r < 4; ++r){
      float s1 = pj[mt][0][r] + pj[mt][1][r] + pj[mt][2][r];
      float s2 = pj[mt][0][r]*pj[mt][0][r] + pj[mt][1][r]*pj[mt][1][r] + pj[mt][2][r]*pj[mt][2][r];
      #pragma unroll
      for (int mk = 1; mk < 16; mk <<= 1){ s1 += __shfl_xor(s1, mk); s2 += __shfl_xor(s2, mk); }
      if (l15 == 0){
        int t = mt*16 + kg*4 + r;
        lnred[t*8 + wave*2]     = s1;
        lnred[t*8 + wave*2 + 1] = s2;
      }
    }
  __syncthreads();
  #pragma unroll
  for (int mt = 0; mt < 4; ++mt)
    #pragma unroll 1
    for (int r = 0; r < 4; ++r){
      int t = mt*16 + kg*4 + r;
      float a1 = lnred[t*8+0] + lnred[t*8+2] + lnred[t*8+4] + lnred[t*8+6];
      float a2 = lnred[t*8+1] + lnred[t*8+3] + lnred[t*8+5] + lnred[t*8+7];
      float mu = a1 * (1.f/192.f);
      float rs = rsqrtf(a2 * (1.f/192.f) - mu*mu + LN_EPS);
      int i = t >> 3, j = t & 7;
      int h0 = ((wh<<3) + i + 4) & 255, w0 = ((ww<<3) + j + 4) & 255;
      size_t base = imgbase + (size_t)(h0*256 + w0)*192;
      #pragma unroll
      for (int nt = 0; nt < 3; ++nt){
        int c = wave*48 + nt*16 + l15;
        x1[base + c] = x[base + c] + (pj[mt][nt][r] - mu)*rs*gv[nt] + bv2[nt];
      }
    }
}

// =====================================================================
// K2 (tier2): MLP + LN2 + residual. Stage from bf16 x1b (pure copies),
// residual from LDS xt, sole writer of f32 xout. Pipelined fc2(c)||fc1(c+1).
// =====================================================================
__global__ __launch_bounds__(256, 3) void k_mlp2(
    float* __restrict__ xout, const u16* __restrict__ x1b,
    const u16* __restrict__ fc1_bf, const float* __restrict__ fc1_b,
    const u16* __restrict__ fc2_bf, const float* __restrict__ fc2_b,
    const float* __restrict__ n2g, const float* __restrict__ n2b)
{
  __shared__ __align__(16) u16 xt[64*200];
  __shared__ __align__(16) u16 hl[64*200];
  float* const lnred = (float*)hl;   // alias: hl dead after last fc2 barrier

  const int tid  = threadIdx.x;
  const int wave = tid >> 6, lane = tid & 63;
  const int kg   = lane >> 4, l15 = lane & 15;
  const size_t t0 = (size_t)blockIdx.x * 64;

  // stage x1b -> xt: 24 chunks of 8 bf16 (16B) per token row  [r12 bugfix: was 12x stride-16]
  for (int s = tid; s < 64*24; s += 256){
    int t = s / 24, c8 = s - t*24;
    *(bf16x8*)(xt + t*200 + c8*8) = gfrag(x1b + (t0 + t)*192 + c8*8);
  }
  f32x4 m2[4][3];
  #pragma unroll
  for (int mt = 0; mt < 4; ++mt)
    #pragma unroll
    for (int nt = 0; nt < 3; ++nt){
      float bv = fc2_b[wave*48 + nt*16 + l15];
      m2[mt][nt] = {bv, bv, bv, bv};
    }
  __syncthreads();   // xt ready

  // ---- fc1 chunk 0 (prologue) ----
  f32x4 a1[4][3];
  #pragma unroll
  for (int mt = 0; mt < 4; ++mt)
    #pragma unroll
    for (int nt = 0; nt < 3; ++nt){
      float bv = fc1_b[wave*48 + nt*16 + l15];
      a1[mt][nt] = {bv, bv, bv, bv};
    }
  #pragma unroll 2
  for (int kt = 0; kt < 6; ++kt){
    bf16x8 af[4];
    #pragma unroll
    for (int mt = 0; mt < 4; ++mt)
      af[mt] = ldsfrag(xt + (mt*16 + l15)*200 + kt*32 + kg*8);
    #pragma unroll
    for (int nt = 0; nt < 3; ++nt){
      bf16x8 bfr = gfrag(fc1_bf + (size_t)(wave*48 + nt*16 + l15)*192 + kt*32 + kg*8);
      #pragma unroll
      for (int mt = 0; mt < 4; ++mt)
        a1[mt][nt] = MFMA16(af[mt], bfr, a1[mt][nt]);
    }
  }

  #pragma unroll 1
  for (int c = 0; c < 4; ++c){
    // ---- light region: gelu + scatter a1 -> hl ----
    #pragma unroll
    for (int mt = 0; mt < 4; ++mt)
      #pragma unroll
      for (int nt = 0; nt < 3; ++nt)
        #pragma unroll
        for (int r = 0; r < 4; ++r)
          hl[(mt*16 + kg*4 + r)*200 + wave*48 + nt*16 + l15] = f2bf(gelu_f(a1[mt][nt][r]));
    __syncthreads();   // hl visible to all waves

    // ---- heavy region: fc2(c) from hl  ||  fc1(c+1) from xt (independent) ----
    #pragma unroll 2
    for (int kt = 0; kt < 6; ++kt){
      bf16x8 af[4];
      #pragma unroll
      for (int mt = 0; mt < 4; ++mt)
        af[mt] = ldsfrag(hl + (mt*16 + l15)*200 + kt*32 + kg*8);
      #pragma unroll
      for (int nt = 0; nt < 3; ++nt){
        bf16x8 bfr = gfrag(fc2_bf + (size_t)(wave*48 + nt*16 + l15)*768 + c*192 + kt*32 + kg*8);
        #pragma unroll
        for (int mt = 0; mt < 4; ++mt)
          m2[mt][nt] = MFMA16(af[mt], bfr, m2[mt][nt]);
      }
    }
    if (c < 3){
      const int cn = c + 1;
      #pragma unroll
      for (int mt = 0; mt < 4; ++mt)
        #pragma unroll
        for (int nt = 0; nt < 3; ++nt){
          float bv = fc1_b[cn*192 + wave*48 + nt*16 + l15];
          a1[mt][nt] = {bv, bv, bv, bv};
        }
      #pragma unroll 2
      for (int kt = 0; kt < 6; ++kt){
        bf16x8 af[4];
        #pragma unroll
        for (int mt = 0; mt < 4; ++mt)
          af[mt] = ldsfrag(xt + (mt*16 + l15)*200 + kt*32 + kg*8);
        #pragma unroll
        for (int nt = 0; nt < 3; ++nt){
          bf16x8 bfr = gfrag(fc1_bf + (size_t)(cn*192 + wave*48 + nt*16 + l15)*192 + kt*32 + kg*8);
          #pragma unroll
          for (int mt = 0; mt < 4; ++mt)
            a1[mt][nt] = MFMA16(af[mt], bfr, a1[mt][nt]);
        }
      }
    }
    __syncthreads();   // all waves done reading hl
  }

  // ---- LN2 + residual (x1 from LDS xt; write f32 out) ----
  float gv[3], bv2[3];
  #pragma unroll
  for (int nt = 0; nt < 3; ++nt){
    int cc = wave*48 + nt*16 + l15;
    gv[nt] = n2g[cc]; bv2[nt] = n2b[cc];
  }
  #pragma unroll
  for (int mt = 0; mt < 4; ++mt)
    #pragma unroll
    for (int r = 0; r < 4; ++r){
      float s1 = m2[mt][0][r] + m2[mt][1][r] + m2[mt][2][r];
      float s2 = m2[mt][0][r]*m2[mt][0][r] + m2[mt][1][r]*m2[mt][1][r] + m2[mt][2][r]*m2[mt][2][r];
      #pragma unroll
      for (int mk = 1; mk < 16; mk <<= 1){ s1 += __shfl_xor(s1, mk); s2 += __shfl_xor(s2, mk); }
      if (l15 == 0){
        int t = mt*16 + kg*4 + r;
        lnred[t*8 + wave*2]     = s1;
        lnred[t*8 + wave*2 + 1] = s2;
      }
    }
  __syncthreads();
  #pragma unroll
  for (int mt = 0; mt < 4; ++mt)
    #pragma unroll 1
    for (int r = 0; r < 4; ++r){
      int t = mt*16 + kg*4 + r;
      float a1s = lnred[t*8+0] + lnred[t*8+2] + lnred[t*8+4] + lnred[t*8+6];
      float a2s = lnred[t*8+1] + lnred[t*8+3] + lnred[t*8+5] + lnred[t*8+7];
      float mu = a1s * (1.f/192.f);
      float rs = rsqrtf(a2s * (1.f/192.f) - mu*mu + LN_EPS);
      size_t base = (t0 + t)*192;
      #pragma unroll
      for (int nt = 0; nt < 3; ++nt){
        int cc = wave*48 + nt*16 + l15;
        float xv = bf2f(xt[t*200 + cc]);
        xout[base + cc] = xv + (m2[mt][nt][r] - mu)*rs*gv[nt] + bv2[nt];
      }
    }
}

// =====================================================================
// K2 (tier1 fallback): MLP in-place on f32 xio (round-11 proven)
// =====================================================================
__global__ __launch_bounds__(256, 3) void k_mlp(
    float* xio, const u16* __restrict__ fc1_bf,
    const float* __restrict__ fc1_b, const u16* __restrict__ fc2_bf,
    const float* __restrict__ fc2_b, const float* __restrict__ n2g,
    const float* __restrict__ n2b)
{
  __shared__ __align__(16) u16 xt[64*200];
  __shared__ __align__(16) u16 hl[64*200];
  __shared__ float lnred[64*8];

  const int tid  = threadIdx.x;
  const int wave = tid >> 6, lane = tid & 63;
  const int kg   = lane >> 4, l15 = lane & 15;
  const size_t t0 = (size_t)blockIdx.x * 64;

  for (int s = tid; s < 64*96; s += 256){
    int t = s / 96, c2 = s - t*96;
    float2 v = LDF2(xio + (t0 + t)*192 + c2*2);
    ST_U32(xt + t*200 + c2*2, pack2(v.x, v.y));
  }
  f32x4 m2[4][3];
  #pragma unroll
  for (int mt = 0; mt < 4; ++mt)
    #pragma unroll
    for (int nt = 0; nt < 3; ++nt){
      float bv = fc2_b[wave*48 + nt*16 + l15];
      m2[mt][nt] = {bv, bv, bv, bv};
    }
  __syncthreads();

  f32x4 a1[4][3];
  #pragma unroll
  for (int mt = 0; mt < 4; ++mt)
    #pragma unroll
    for (int nt = 0; nt < 3; ++nt){
      float bv = fc1_b[wave*48 + nt*16 + l15];
      a1[mt][nt] = {bv, bv, bv, bv};
    }
  #pragma unroll 2
  for (int kt = 0; kt < 6; ++kt){
    bf16x8 af[4];
    #pragma unroll
    for (int mt = 0; mt < 4; ++mt)
      af[mt] = ldsfrag(xt + (mt*16 + l15)*200 + kt*32 + kg*8);
    #pragma unroll
    for (int nt = 0; nt < 3; ++nt){
      bf16x8 bfr = gfrag(fc1_bf + (size_t)(wave*48 + nt*16 + l15)*192 + kt*32 + kg*8);
      #pragma unroll
      for (int mt = 0; mt < 4; ++mt)
        a1[mt][nt] = MFMA16(af[mt], bfr, a1[mt][nt]);
    }
  }

  #pragma unroll 1
  for (int c = 0; c < 4; ++c){
    #pragma unroll
    for (int mt = 0; mt < 4; ++mt)
      #pragma unroll
      for (int nt = 0; nt < 3; ++nt)
        #pragma unroll
        for (int r = 0; r < 4; ++r)
          hl[(mt*16 + kg*4 + r)*200 + wave*48 + nt*16 + l15] = f2bf(gelu_f(a1[mt][nt][r]));
    __syncthreads();

    #pragma unroll 2
    for (int kt = 0; kt < 6; ++kt){
      bf16x8 af[4];
      #pragma unroll
      for (int mt = 0; mt < 4; ++mt)
        af[mt] = ldsfrag(hl + (mt*16 + l15)*200 + kt*32 + kg*8);
      #pragma unroll
      for (int nt = 0; nt < 3; ++nt){
        bf16x8 bfr = gfrag(fc2_bf + (size_t)(wave*48 + nt*16 + l15)*768 + c*192 + kt*32 + kg*8);
        #pragma unroll
        for (int mt = 0; mt < 4; ++mt)
          m2[mt][nt] = MFMA16(af[mt], bfr, m2[mt][nt]);
      }
    }
    if (c < 3){
      const int cn = c + 1;
      #pragma unroll
      for (int mt = 0; mt < 4; ++mt)
        #pragma unroll
        for (int nt = 0; nt < 3; ++nt){
          float bv = fc1_b[cn*192 + wave*48 + nt*16 + l15];
          a1[mt][nt] = {bv, bv, bv, bv};
        }
      #pragma unroll 2
      for (int kt = 0; kt < 6; ++kt){
        bf16x8 af[4];
        #pragma unroll
        for (int mt = 0; mt < 4; ++mt)
          af[mt] = ldsfrag(xt + (mt*16 + l15)*200 + kt*32 + kg*8);
        #pragma unroll
        for (int nt = 0; nt < 3; ++nt){
          bf16x8 bfr = gfrag(fc1_bf + (size_t)(cn*192 + wave*48 + nt*16 + l15)*192 + kt*32 + kg*8);
          #pragma unroll
          for (int mt = 0; mt < 4; ++mt)
            a1[mt][nt] = MFMA16(af[mt], bfr, a1[mt][nt]);
        }
      }
    }
    __syncthreads();
  }

  float gv[3], bv2[3];
  #pragma unroll
  for (int nt = 0; nt < 3; ++nt){
    int cc = wave*48 + nt*16 + l15;
    gv[nt] = n2g[cc]; bv2[nt] = n2b[cc];
  }
  #pragma unroll
  for (int mt = 0; mt < 4; ++mt)
    #pragma unroll
    for (int r = 0; r < 4; ++r){
      float s1 = m2[mt][0][r] + m2[mt][1][r] + m2[mt][2][r];
      float s2 = m2[mt][0][r]*m2[mt][0][r] + m2[mt][1][r]*m2[mt][1][r] + m2[mt][2][r]*m2[mt][2][r];
      #pragma unroll
      for (int mk = 1; mk < 16; mk <<= 1){ s1 += __shfl_xor(s1, mk); s2 += __shfl_xor(s2, mk); }
      if (l15 == 0){
        int t = mt*16 + kg*4 + r;
        lnred[t*8 + wave*2]     = s1;
        lnred[t*8 + wave*2 + 1] = s2;
      }
    }
  __syncthreads();
  #pragma unroll
  for (int mt = 0; mt < 4; ++mt)
    #pragma unroll 1
    for (int r = 0; r < 4; ++r){
      int t = mt*16 + kg*4 + r;
      float a1s = lnred[t*8+0] + lnred[t*8+2] + lnred[t*8+4] + lnred[t*8+6];
      float a2s = lnred[t*8+1] + lnred[t*8+3] + lnred[t*8+5] + lnred[t*8+7];
      float mu = a1s * (1.f/192.f);
      float rs = rsqrtf(a2s * (1.f/192.f) - mu*mu + LN_EPS);
      size_t base = (t0 + t)*192;
      #pragma unroll
      for (int nt = 0; nt < 3; ++nt){
        int cc = wave*48 + nt*16 + l15;
        xio[base + cc] = xio[base + cc] + (m2[mt][nt][r] - mu)*rs*gv[nt] + bv2[nt];
      }
    }
}

extern "C" void kernel_launch(void* const* d_in, const int* in_sizes, int n_in,
                              void* d_out, int out_size, void* d_ws, size_t ws_size,
                              hipStream_t stream)
{
  const float* x      = (const float*)d_in[0];
  const float* mask   = (const float*)d_in[1];
  const int*   relidx = (const int*)d_in[2];
  const float* qkv_w  = (const float*)d_in[3];
  const float* qkv_b  = (const float*)d_in[4];
  const float* proj_w = (const float*)d_in[5];
  const float* proj_b = (const float*)d_in[6];
  const float* rpb    = (const float*)d_in[7];
  const float* n1g    = (const float*)d_in[8];
  const float* n1b    = (const float*)d_in[9];
  const float* n2g    = (const float*)d_in[10];
  const float* n2b    = (const float*)d_in[11];
  const float* fc1_w  = (const float*)d_in[12];
  const float* fc1_b  = (const float*)d_in[13];
  const float* fc2_w  = (const float*)d_in[14];
  const float* fc2_b  = (const float*)d_in[15];
  float* xio = (float*)d_out;

  u16* qkv_bf  = (u16*)d_ws;
  u16* proj_bf = qkv_bf + NQKV;
  u16* fc1_bf  = proj_bf + NPRJ;
  u16* fc2_bf  = fc1_bf + NFC;
  float* rpbm  = (float*)(fc2_bf + NFC);
  float* rpbmT = rpbm + 6*4096;
  u16* Qg  = (u16*)((char*)d_ws + WS_SPLIT_HDR);
  u16* Kg  = Qg + QKV_SLAB;
  u16* VTg = Kg + QKV_SLAB;
  u16* x1b = VTg + QKV_SLAB;

  const int tier = (ws_size >= WS_SPLIT2_NEED) ? 2 : (ws_size >= WS_SPLIT_NEED) ? 1 : 0;

  k_prep<<<dim3(512), dim3(256), 0, stream>>>(qkv_w, proj_w, fc1_w, fc2_w,
      rpb, relidx, qkv_bf, proj_bf, fc1_bf, fc2_bf, rpbm, rpbmT, tier ? 1 : 0);
  if (tier){
    k_qkv<<<dim3(4096), dim3(256), 0, stream>>>(x, qkv_bf, qkv_b, Qg, Kg, VTg);
    if (tier == 2){
      k_attn2<<<dim3(4096), dim3(256), 0, stream>>>(x, mask, rpbmT, Qg, Kg, VTg,
          proj_bf, proj_b, n1g, n1b, (float*)nullptr, x1b);
      k_mlp2<<<dim3(4096), dim3(256), 0, stream>>>(xio, x1b, fc1_bf, fc1_b,
          fc2_bf, fc2_b, n2g, n2b);
    } else {
      k_attn2<<<dim3(4096), dim3(256), 0, stream>>>(x, mask, rpbmT, Qg, Kg, VTg,
          proj_bf, proj_b, n1g, n1b, xio, (u16*)nullptr);
      k_mlp<<<dim3(4096), dim3(256), 0, stream>>>(xio, fc1_bf, fc1_b, fc2_bf, fc2_b,
          n2g, n2b);
    }
  } else {
    k_attn<<<dim3(4096), dim3(256), 0, stream>>>(x, mask, rpbm, qkv_bf, qkv_b,
        proj_bf, proj_b, n1g, n1b, xio);
    k_mlp<<<dim3(4096), dim3(256), 0, stream>>>(xio, fc1_bf, fc1_b, fc2_bf, fc2_b,
        n2g, n2b);
  }
}

// Round 14
// 848.152 us; speedup vs baseline: 1.0985x; 1.0985x over previous
//
#include <hip/hip_runtime.h>
#include <hip/hip_bf16.h>
#include <math.h>

typedef unsigned short u16;
typedef unsigned int   u32;
typedef __attribute__((ext_vector_type(8))) short bf16x8;   // 8 bf16 = 4 VGPR
typedef __attribute__((ext_vector_type(4))) float f32x4;

__device__ __forceinline__ u16 f2bf(float f){
  u32 u = __float_as_uint(f);
  u += 0x7fffu + ((u>>16)&1u);          // RNE; inputs never NaN
  return (u16)(u>>16);
}
__device__ __forceinline__ u32 pack2(float a, float b){
  return (u32)f2bf(a) | ((u32)f2bf(b)<<16);
}
__device__ __forceinline__ float bf2f(u16 u){ return __uint_as_float(((u32)u)<<16); }
__device__ __forceinline__ float2 LDF2(const float* p){ return *(const float2*)p; }
__device__ __forceinline__ float gelu_f(float v){
  float t = __expf(1.5957691216057308f * fmaf(0.044715f*v, v*v, v));
  return v - v*__builtin_amdgcn_rcpf(t + 1.0f);   // tanh-form GELU, fast rcp
}

#define ST_U32(p,v) (*(u32*)(p) = (v))
#define MFMA16(a,b,c) __builtin_amdgcn_mfma_f32_16x16x32_bf16((a),(b),(c),0,0,0)

__device__ __forceinline__ bf16x8 ldsfrag(const u16* p){ return *(const bf16x8*)p; }
__device__ __forceinline__ bf16x8 gfrag(const u16* p){ return *(const bf16x8*)p; }

constexpr float SCALE_Q = 0.17677669529663687f;  // 32^-0.5
constexpr float LN_EPS  = 1e-5f;

// ws element counts (u16)
#define NQKV 110592
#define NPRJ 36864
#define NFC  147456
#define QKV_SLAB 50331648ull        // 4096*64*192 u16 per slab (Q/K/VT)
#define WS_WEIGHTS_B 884736ull
#define WS_RPBM_B    98304ull
#define WS_SPLIT_HDR (WS_WEIGHTS_B + 2*WS_RPBM_B)             // 1081344 B
#define WS_SPLIT_NEED  (WS_SPLIT_HDR + 3ull*QKV_SLAB*2ull)    // ~303 MB

// =====================================================================
// K0: weight f32->bf16 conversion + rpb gather (row-major, + transposed)
// =====================================================================
__global__ void k_prep(const float* __restrict__ qkv_w, const float* __restrict__ proj_w,
                       const float* __restrict__ fc1_w, const float* __restrict__ fc2_w,
                       const float* __restrict__ rpb, const int* __restrict__ relidx,
                       u16* __restrict__ qkv_bf, u16* __restrict__ proj_bf,
                       u16* __restrict__ fc1_bf, u16* __restrict__ fc2_bf,
                       float* __restrict__ rpbm, float* __restrict__ rpbmT, int mode)
{
  int stride = gridDim.x * blockDim.x;
  int t = blockIdx.x * blockDim.x + threadIdx.x;
  for (int i = t; i < NQKV; i += stride) qkv_bf[i] = f2bf(qkv_w[i]);
  for (int i = t; i < NPRJ; i += stride) proj_bf[i] = f2bf(proj_w[i]);
  for (int i = t; i < NFC;  i += stride) fc1_bf[i]  = f2bf(fc1_w[i]);
  for (int i = t; i < NFC;  i += stride) fc2_bf[i]  = f2bf(fc2_w[i]);
  for (int i = t; i < 6*4096; i += stride){
    int h = i >> 12, ij = i & 4095;
    rpbm[i] = rpb[relidx[ij]*6 + h];
  }
  if (mode){
    for (int i = t; i < 6*4096; i += stride){
      int h = i >> 12, ij = i & 4095;           // ij = col*64 + row (transposed)
      int col = ij >> 6, row = ij & 63;
      rpbmT[i] = rpb[relidx[row*64 + col]*6 + h];
    }
  }
}

// =====================================================================
// K1a: per-window qkv GEMM -> Qg (scaled), Kg, VTg (transposed)
// =====================================================================
__global__ __launch_bounds__(256, 4) void k_qkv(
    const float* __restrict__ x, const u16* __restrict__ qkv_bf,
    const float* __restrict__ qkv_b,
    u16* __restrict__ Qg, u16* __restrict__ Kg, u16* __restrict__ VTg)
{
  __shared__ __align__(16) u16 xw[64*200];
  const int tid = threadIdx.x, wave = tid >> 6, lane = tid & 63;
  const int kg = lane >> 4, l15 = lane & 15;
  const int wi = blockIdx.x, b = wi >> 10, wm = wi & 1023;
  const int wh = wm >> 5, ww = wm & 31;
  const size_t imgbase = (size_t)b * (256*256*192);

  for (int s = tid; s < 64*96; s += 256){
    int t = s / 96, c2 = s - t*96;
    int i = t >> 3, j = t & 7;
    int h0 = ((wh<<3) + i + 4) & 255;
    int w0 = ((ww<<3) + j + 4) & 255;
    float2 v = LDF2(x + imgbase + (size_t)(h0*256 + w0)*192 + c2*2);
    ST_U32(xw + t*200 + c2*2, pack2(v.x, v.y));
  }
  __syncthreads();

  const size_t wbase = (size_t)wi * 12288;
  #pragma unroll 1
  for (int batch = 0; batch < 3; ++batch){
    const int col0 = wave*144 + batch*48;
    f32x4 a[4][3];
    #pragma unroll
    for (int j = 0; j < 3; ++j){
      float bv = qkv_b[col0 + j*16 + l15];
      #pragma unroll
      for (int mt = 0; mt < 4; ++mt) a[mt][j] = {bv, bv, bv, bv};
    }
    #pragma unroll 2
    for (int kt = 0; kt < 6; ++kt){
      bf16x8 af[4];
      #pragma unroll
      for (int mt = 0; mt < 4; ++mt)
        af[mt] = ldsfrag(xw + (mt*16 + l15)*200 + kt*32 + kg*8);
      #pragma unroll
      for (int j = 0; j < 3; ++j){
        bf16x8 bfr = gfrag(qkv_bf + (col0 + j*16 + l15)*192 + kt*32 + kg*8);
        #pragma unroll
        for (int mt = 0; mt < 4; ++mt)
          a[mt][j] = MFMA16(af[mt], bfr, a[mt][j]);
      }
    }
    #pragma unroll
    for (int j = 0; j < 3; ++j){
      int colg = col0 + j*16 + l15;          // uniform section per (wave,batch,j)
      if (colg < 192){
        #pragma unroll
        for (int mt = 0; mt < 4; ++mt)
          #pragma unroll
          for (int r = 0; r < 4; ++r)
            Qg[wbase + (size_t)(mt*16 + kg*4 + r)*192 + colg] = f2bf(a[mt][j][r]*SCALE_Q);
      } else if (colg < 384){
        #pragma unroll
        for (int mt = 0; mt < 4; ++mt)
          #pragma unroll
          for (int r = 0; r < 4; ++r)
            Kg[wbase + (size_t)(mt*16 + kg*4 + r)*192 + (colg - 192)] = f2bf(a[mt][j][r]);
      } else {
        #pragma unroll
        for (int mt = 0; mt < 4; ++mt){
          ushort4 pk = { f2bf(a[mt][j][0]), f2bf(a[mt][j][1]),
                         f2bf(a[mt][j][2]), f2bf(a[mt][j][3]) };
          *(ushort4*)(VTg + wbase + (size_t)(colg - 384)*64 + mt*16 + kg*4) = pk;
        }
      }
    }
  }
}

// =====================================================================
// K1b FUSED: attention core + proj + LN1 + MLP + LN2 -> final out (f32)
// x1 never leaves LDS. One block per window, 4 waves.
// LDS: xt = PV-out(attn) then x1(mlp); rb = prb(attn)/lnred/hl(mlp).
// =====================================================================
__global__ __launch_bounds__(256, 3) void k_fused(
    const float* __restrict__ x, const float* __restrict__ mask,
    const float* __restrict__ rpbmT,
    const u16* __restrict__ Qg, const u16* __restrict__ Kg,
    const u16* __restrict__ VTg,
    const u16* __restrict__ proj_bf, const float* __restrict__ proj_b,
    const float* __restrict__ n1g, const float* __restrict__ n1b,
    const u16* __restrict__ fc1_bf, const float* __restrict__ fc1_b,
    const u16* __restrict__ fc2_bf, const float* __restrict__ fc2_b,
    const float* __restrict__ n2g, const float* __restrict__ n2b,
    float* __restrict__ out)
{
  __shared__ __align__(16) u16 xt[64*200];   // attn PV-out -> x1 (bf16)
  __shared__ __align__(16) u16 rb[64*200];   // prb (9216B) -> lnred -> hl
  u16* const prb = rb;
  u16* const hl  = rb;
  float* const lnred = (float*)rb;

  const int tid = threadIdx.x, wave = tid >> 6, lane = tid & 63;
  const int kg = lane >> 4, l15 = lane & 15;
  const int wi = blockIdx.x, b = wi >> 10, wm = wi & 1023;
  const int wh = wm >> 5, ww = wm & 31;
  const bool hasmask = (wh == 31) || (ww == 31);
  const size_t imgbase = (size_t)b * (256*256*192);
  const size_t wbase = (size_t)wi * 12288;

  // ---------------- attention core (per head, barrier-free) ----------------
  f32x4 pj[4][3];
  #pragma unroll
  for (int mt = 0; mt < 4; ++mt)
    #pragma unroll
    for (int nt = 0; nt < 3; ++nt){
      float bv = proj_b[wave*48 + nt*16 + l15];
      pj[mt][nt] = {bv, bv, bv, bv};
    }

  #pragma unroll 1
  for (int h = 0; h < 6; ++h){
    const f32x4 z = {0.f, 0.f, 0.f, 0.f};
    bf16x8 qf = gfrag(Qg + wbase + (size_t)(wave*16 + l15)*192 + h*32 + kg*8);
    f32x4 at[4];
    #pragma unroll
    for (int nt = 0; nt < 4; ++nt){
      bf16x8 kf = gfrag(Kg + wbase + (size_t)(nt*16 + l15)*192 + h*32 + kg*8);
      at[nt] = MFMA16(qf, kf, z);
    }
    {
      const float* rbp = rpbmT + h*4096;
      #pragma unroll
      for (int nt = 0; nt < 4; ++nt){
        int cidx = (nt*16 + l15)*64 + wave*16 + kg*4;
        float4 r4 = *(const float4*)(rbp + cidx);
        at[nt][0] += r4.x; at[nt][1] += r4.y;
        at[nt][2] += r4.z; at[nt][3] += r4.w;
      }
    }
    if (hasmask){
      const float* mb = mask + (size_t)wm*4096;
      #pragma unroll
      for (int nt = 0; nt < 4; ++nt){
        int cidx = (nt*16 + l15)*64 + wave*16 + kg*4;
        float4 m4 = *(const float4*)(mb + cidx);
        at[nt][0] += m4.x; at[nt][1] += m4.y;
        at[nt][2] += m4.z; at[nt][3] += m4.w;
      }
    }
    #pragma unroll
    for (int r = 0; r < 4; ++r){
      float m0 = fmaxf(fmaxf(at[0][r], at[1][r]), fmaxf(at[2][r], at[3][r]));
      #pragma unroll
      for (int mk = 1; mk < 16; mk <<= 1) m0 = fmaxf(m0, __shfl_xor(m0, mk));
      float s = 0.f;
      #pragma unroll
      for (int nt = 0; nt < 4; ++nt){ at[nt][r] = __expf(at[nt][r] - m0); s += at[nt][r]; }
      #pragma unroll
      for (int mk = 1; mk < 16; mk <<= 1) s += __shfl_xor(s, mk);
      float inv = __builtin_amdgcn_rcpf(s);
      #pragma unroll
      for (int nt = 0; nt < 4; ++nt) at[nt][r] *= inv;
    }
    #pragma unroll
    for (int nt = 0; nt < 4; ++nt)
      #pragma unroll
      for (int r = 0; r < 4; ++r)
        prb[(wave*16 + kg*4 + r)*72 + nt*16 + l15] = f2bf(at[nt][r]);
    // (prb rows wave-local; no barrier needed)
    {
      f32x4 ov[2] = {z, z};
      #pragma unroll
      for (int kt = 0; kt < 2; ++kt){
        bf16x8 pf = ldsfrag(prb + (wave*16 + l15)*72 + kt*32 + kg*8);
        #pragma unroll
        for (int d = 0; d < 2; ++d){
          bf16x8 vf = gfrag(VTg + wbase + (size_t)(h*32 + d*16 + l15)*64 + kt*32 + kg*8);
          ov[d] = MFMA16(pf, vf, ov[d]);
        }
      }
      #pragma unroll
      for (int d = 0; d < 2; ++d)
        #pragma unroll
        for (int r = 0; r < 4; ++r)
          xt[(wave*16 + kg*4 + r)*200 + h*32 + d*16 + l15] = f2bf(ov[d][r]);
    }
  }
  __syncthreads();   // PV-out complete, prb dead

  // ---------------- proj (reads xt) ----------------
  #pragma unroll 2
  for (int kt = 0; kt < 6; ++kt){
    bf16x8 af[4];
    #pragma unroll
    for (int mt = 0; mt < 4; ++mt)
      af[mt] = ldsfrag(xt + (mt*16 + l15)*200 + kt*32 + kg*8);
    #pragma unroll
    for (int nt = 0; nt < 3; ++nt){
      bf16x8 bfr = gfrag(proj_bf + (wave*48 + nt*16 + l15)*192 + kt*32 + kg*8);
      #pragma unroll
      for (int mt = 0; mt < 4; ++mt)
        pj[mt][nt] = MFMA16(af[mt], bfr, pj[mt][nt]);
    }
  }

  // ---------------- LN1 + residual -> y (bf16) overwrites xt ----------------
  {
    float gv[3], bv2[3];
    #pragma unroll
    for (int nt = 0; nt < 3; ++nt){
      int c = wave*48 + nt*16 + l15;
      gv[nt] = n1g[c]; bv2[nt] = n1b[c];
    }
    #pragma unroll
    for (int mt = 0; mt < 4; ++mt)
      #pragma unroll
      for (int r = 0; r < 4; ++r){
        float s1 = pj[mt][0][r] + pj[mt][1][r] + pj[mt][2][r];
        float s2 = pj[mt][0][r]*pj[mt][0][r] + pj[mt][1][r]*pj[mt][1][r] + pj[mt][2][r]*pj[mt][2][r];
        #pragma unroll
        for (int mk = 1; mk < 16; mk <<= 1){ s1 += __shfl_xor(s1, mk); s2 += __shfl_xor(s2, mk); }
        if (l15 == 0){
          int t = mt*16 + kg*4 + r;
          lnred[t*8 + wave*2]     = s1;
          lnred[t*8 + wave*2 + 1] = s2;
        }
      }
    __syncthreads();   // lnred ready; also fences all proj reads of xt
    #pragma unroll
    for (int mt = 0; mt < 4; ++mt)
      #pragma unroll 1
      for (int r = 0; r < 4; ++r){
        int t = mt*16 + kg*4 + r;
        float a1s = lnred[t*8+0] + lnred[t*8+2] + lnred[t*8+4] + lnred[t*8+6];
        float a2s = lnred[t*8+1] + lnred[t*8+3] + lnred[t*8+5] + lnred[t*8+7];
        float mu = a1s * (1.f/192.f);
        float rs = rsqrtf(a2s * (1.f/192.f) - mu*mu + LN_EPS);
        int i = t >> 3, j = t & 7;
        int h0 = ((wh<<3) + i + 4) & 255, w0 = ((ww<<3) + j + 4) & 255;
        size_t base = imgbase + (size_t)(h0*256 + w0)*192;
        #pragma unroll
        for (int nt = 0; nt < 3; ++nt){
          int c = wave*48 + nt*16 + l15;
          float y = x[base + c] + (pj[mt][nt][r] - mu)*rs*gv[nt] + bv2[nt];
          xt[t*200 + c] = f2bf(y);
        }
      }
  }
  __syncthreads();   // x1 (y) staged in xt; lnred consumed

  // ---------------- MLP (pipelined fc2(c) || fc1(c+1)) ----------------
  f32x4 m2[4][3];
  #pragma unroll
  for (int mt = 0; mt < 4; ++mt)
    #pragma unroll
    for (int nt = 0; nt < 3; ++nt){
      float bv = fc2_b[wave*48 + nt*16 + l15];
      m2[mt][nt] = {bv, bv, bv, bv};
    }
  f32x4 a1[4][3];
  #pragma unroll
  for (int mt = 0; mt < 4; ++mt)
    #pragma unroll
    for (int nt = 0; nt < 3; ++nt){
      float bv = fc1_b[wave*48 + nt*16 + l15];
      a1[mt][nt] = {bv, bv, bv, bv};
    }
  #pragma unroll 2
  for (int kt = 0; kt < 6; ++kt){
    bf16x8 af[4];
    #pragma unroll
    for (int mt = 0; mt < 4; ++mt)
      af[mt] = ldsfrag(xt + (mt*16 + l15)*200 + kt*32 + kg*8);
    #pragma unroll
    for (int nt = 0; nt < 3; ++nt){
      bf16x8 bfr = gfrag(fc1_bf + (size_t)(wave*48 + nt*16 + l15)*192 + kt*32 + kg*8);
      #pragma unroll
      for (int mt = 0; mt < 4; ++mt)
        a1[mt][nt] = MFMA16(af[mt], bfr, a1[mt][nt]);
    }
  }

  #pragma unroll 1
  for (int c = 0; c < 4; ++c){
    #pragma unroll
    for (int mt = 0; mt < 4; ++mt)
      #pragma unroll
      for (int nt = 0; nt < 3; ++nt)
        #pragma unroll
        for (int r = 0; r < 4; ++r)
          hl[(mt*16 + kg*4 + r)*200 + wave*48 + nt*16 + l15] = f2bf(gelu_f(a1[mt][nt][r]));
    __syncthreads();

    #pragma unroll 2
    for (int kt = 0; kt < 6; ++kt){
      bf16x8 af[4];
      #pragma unroll
      for (int mt = 0; mt < 4; ++mt)
        af[mt] = ldsfrag(hl + (mt*16 + l15)*200 + kt*32 + kg*8);
      #pragma unroll
      for (int nt = 0; nt < 3; ++nt){
        bf16x8 bfr = gfrag(fc2_bf + (size_t)(wave*48 + nt*16 + l15)*768 + c*192 + kt*32 + kg*8);
        #pragma unroll
        for (int mt = 0; mt < 4; ++mt)
          m2[mt][nt] = MFMA16(af[mt], bfr, m2[mt][nt]);
      }
    }
    if (c < 3){
      const int cn = c + 1;
      #pragma unroll
      for (int mt = 0; mt < 4; ++mt)
        #pragma unroll
        for (int nt = 0; nt < 3; ++nt){
          float bv = fc1_b[cn*192 + wave*48 + nt*16 + l15];
          a1[mt][nt] = {bv, bv, bv, bv};
        }
      #pragma unroll 2
      for (int kt = 0; kt < 6; ++kt){
        bf16x8 af[4];
        #pragma unroll
        for (int mt = 0; mt < 4; ++mt)
          af[mt] = ldsfrag(xt + (mt*16 + l15)*200 + kt*32 + kg*8);
        #pragma unroll
        for (int nt = 0; nt < 3; ++nt){
          bf16x8 bfr = gfrag(fc1_bf + (size_t)(cn*192 + wave*48 + nt*16 + l15)*192 + kt*32 + kg*8);
          #pragma unroll
          for (int mt = 0; mt < 4; ++mt)
            a1[mt][nt] = MFMA16(af[mt], bfr, a1[mt][nt]);
        }
      }
    }
    __syncthreads();   // hl consumed
  }

  // ---------------- LN2 + residual (x1 from xt), final f32 write ----------------
  {
    float gv[3], bv2[3];
    #pragma unroll
    for (int nt = 0; nt < 3; ++nt){
      int cc = wave*48 + nt*16 + l15;
      gv[nt] = n2g[cc]; bv2[nt] = n2b[cc];
    }
    #pragma unroll
    for (int mt = 0; mt < 4; ++mt)
      #pragma unroll
      for (int r = 0; r < 4; ++r){
        float s1 = m2[mt][0][r] + m2[mt][1][r] + m2[mt][2][r];
        float s2 = m2[mt][0][r]*m2[mt][0][r] + m2[mt][1][r]*m2[mt][1][r] + m2[mt][2][r]*m2[mt][2][r];
        #pragma unroll
        for (int mk = 1; mk < 16; mk <<= 1){ s1 += __shfl_xor(s1, mk); s2 += __shfl_xor(s2, mk); }
        if (l15 == 0){
          int t = mt*16 + kg*4 + r;
          lnred[t*8 + wave*2]     = s1;
          lnred[t*8 + wave*2 + 1] = s2;
        }
      }
    __syncthreads();
    #pragma unroll
    for (int mt = 0; mt < 4; ++mt)
      #pragma unroll 1
      for (int r = 0; r < 4; ++r){
        int t = mt*16 + kg*4 + r;
        float a1s = lnred[t*8+0] + lnred[t*8+2] + lnred[t*8+4] + lnred[t*8+6];
        float a2s = lnred[t*8+1] + lnred[t*8+3] + lnred[t*8+5] + lnred[t*8+7];
        float mu = a1s * (1.f/192.f);
        float rs = rsqrtf(a2s * (1.f/192.f) - mu*mu + LN_EPS);
        int i = t >> 3, j = t & 7;
        int h0 = ((wh<<3) + i + 4) & 255, w0 = ((ww<<3) + j + 4) & 255;
        size_t base = imgbase + (size_t)(h0*256 + w0)*192;
        #pragma unroll
        for (int nt = 0; nt < 3; ++nt){
          int cc = wave*48 + nt*16 + l15;
          float xv = bf2f(xt[t*200 + cc]);
          out[base + cc] = xv + (m2[mt][nt][r] - mu)*rs*gv[nt] + bv2[nt];
        }
      }
  }
}

// =====================================================================
// K1 (tier0 fallback): monolithic attention (round-4 proven)
// =====================================================================
__global__ __launch_bounds__(256, 3) void k_attn(
    const float* __restrict__ x, const float* __restrict__ mask,
    const float* __restrict__ rpbm, const u16* __restrict__ qkv_bf,
    const float* __restrict__ qkv_b, const u16* __restrict__ proj_bf,
    const float* __restrict__ proj_b, const float* __restrict__ n1g,
    const float* __restrict__ n1b, float* __restrict__ x1)
{
  __shared__ __align__(16) u16 xw[64*200];
  __shared__ __align__(16) u16 qkvh[64*72];
  __shared__ __align__(16) u16 vT[32*72];
  __shared__ __align__(16) u16 prb[64*72];
  __shared__ __align__(16) u16 outh[64*40];
  float* lnred = (float*)outh;

  const int tid  = threadIdx.x;
  const int wave = tid >> 6, lane = tid & 63;
  const int kg   = lane >> 4, l15 = lane & 15;
  const int wi = blockIdx.x;
  const int b  = wi >> 10, wm = wi & 1023;
  const int wh = wm >> 5,  ww = wm & 31;
  const size_t imgbase = (size_t)b * (256*256*192);

  for (int s = tid; s < 64*96; s += 256){
    int t = s / 96, c2 = s - t*96;
    int i = t >> 3, j = t & 7;
    int h0 = ((wh<<3) + i + 4) & 255;
    int w0 = ((ww<<3) + j + 4) & 255;
    float2 v = LDF2(x + imgbase + (size_t)(h0*256 + w0)*192 + c2*2);
    ST_U32(xw + t*200 + c2*2, pack2(v.x, v.y));
  }

  f32x4 pj[4][3];
  #pragma unroll
  for (int mt = 0; mt < 4; ++mt)
    #pragma unroll
    for (int nt = 0; nt < 3; ++nt){
      float bv = proj_b[wave*48 + nt*16 + l15];
      pj[mt][nt] = {bv, bv, bv, bv};
    }
  __syncthreads();

  #pragma unroll 1
  for (int h = 0; h < 6; ++h){
    f32x4 qa[6];
    #pragma unroll
    for (int nt = 0; nt < 6; ++nt){
      float bv = qkv_b[(nt>>1)*192 + h*32 + (nt&1)*16 + l15];
      qa[nt] = {bv, bv, bv, bv};
    }
    #pragma unroll 2
    for (int kt = 0; kt < 6; ++kt){
      bf16x8 af = ldsfrag(xw + (wave*16 + l15)*200 + kt*32 + kg*8);
      #pragma unroll
      for (int nt = 0; nt < 6; ++nt){
        bf16x8 bfr = gfrag(qkv_bf + ((nt>>1)*192 + h*32 + (nt&1)*16 + l15)*192 + kt*32 + kg*8);
        qa[nt] = MFMA16(af, bfr, qa[nt]);
      }
    }
    #pragma unroll
    for (int nt = 0; nt < 2; ++nt)
      #pragma unroll
      for (int r = 0; r < 4; ++r)
        qkvh[(wave*16 + kg*4 + r)*72 + nt*16 + l15] = f2bf(qa[nt][r]*SCALE_Q);
    #pragma unroll
    for (int nt = 2; nt < 4; ++nt)
      #pragma unroll
      for (int r = 0; r < 4; ++r)
        qkvh[(wave*16 + kg*4 + r)*72 + 32 + (nt-2)*16 + l15] = f2bf(qa[nt][r]);
    #pragma unroll
    for (int nt = 4; nt < 6; ++nt)
      #pragma unroll
      for (int r = 0; r < 4; ++r)
        vT[((nt-4)*16 + l15)*72 + wave*16 + kg*4 + r] = f2bf(qa[nt][r]);
    __syncthreads();

    f32x4 at[4];
    {
      const f32x4 z = {0.f, 0.f, 0.f, 0.f};
      bf16x8 qf = ldsfrag(qkvh + (wave*16 + l15)*72 + kg*8);
      #pragma unroll
      for (int nt = 0; nt < 4; ++nt){
        bf16x8 kf = ldsfrag(qkvh + (nt*16 + l15)*72 + 32 + kg*8);
        at[nt] = MFMA16(qf, kf, z);
      }
    }
    {
      const float* rbp = rpbm + h*4096;
      const float* mb = mask + (size_t)wm*4096;
      #pragma unroll
      for (int nt = 0; nt < 4; ++nt)
        #pragma unroll
        for (int r = 0; r < 4; ++r){
          int idx = (wave*16 + kg*4 + r)*64 + nt*16 + l15;
          at[nt][r] += rbp[idx] + mb[idx];
        }
    }
    #pragma unroll
    for (int r = 0; r < 4; ++r){
      float m0 = fmaxf(fmaxf(at[0][r], at[1][r]), fmaxf(at[2][r], at[3][r]));
      #pragma unroll
      for (int mk = 1; mk < 16; mk <<= 1) m0 = fmaxf(m0, __shfl_xor(m0, mk));
      float s = 0.f;
      #pragma unroll
      for (int nt = 0; nt < 4; ++nt){ at[nt][r] = __expf(at[nt][r] - m0); s += at[nt][r]; }
      #pragma unroll
      for (int mk = 1; mk < 16; mk <<= 1) s += __shfl_xor(s, mk);
      float inv = __builtin_amdgcn_rcpf(s);
      #pragma unroll
      for (int nt = 0; nt < 4; ++nt) at[nt][r] *= inv;
    }
    #pragma unroll
    for (int nt = 0; nt < 4; ++nt)
      #pragma unroll
      for (int r = 0; r < 4; ++r)
        prb[(wave*16 + kg*4 + r)*72 + nt*16 + l15] = f2bf(at[nt][r]);

    {
      f32x4 ov[2] = {{0,0,0,0},{0,0,0,0}};
      #pragma unroll
      for (int kt = 0; kt < 2; ++kt){
        bf16x8 pf = ldsfrag(prb + (wave*16 + l15)*72 + kt*32 + kg*8);
        #pragma unroll
        for (int nt = 0; nt < 2; ++nt){
          bf16x8 vf = ldsfrag(vT + (nt*16 + l15)*72 + kt*32 + kg*8);
          ov[nt] = MFMA16(pf, vf, ov[nt]);
        }
      }
      #pragma unroll
      for (int nt = 0; nt < 2; ++nt)
        #pragma unroll
        for (int r = 0; r < 4; ++r)
          outh[(wave*16 + kg*4 + r)*40 + nt*16 + l15] = f2bf(ov[nt][r]);
    }
    __syncthreads();

    {
      bf16x8 pw[3];
      #pragma unroll
      for (int nt = 0; nt < 3; ++nt)
        pw[nt] = gfrag(proj_bf + (wave*48 + nt*16 + l15)*192 + h*32 + kg*8);
      #pragma unroll
      for (int mt = 0; mt < 4; ++mt){
        bf16x8 af = ldsfrag(outh + (mt*16 + l15)*40 + kg*8);
        #pragma unroll
        for (int nt = 0; nt < 3; ++nt)
          pj[mt][nt] = MFMA16(af, pw[nt], pj[mt][nt]);
      }
    }
    __syncthreads();
  }

  float gv[3], bv2[3];
  #pragma unroll
  for (int nt = 0; nt < 3; ++nt){
    int c = wave*48 + nt*16 + l15;
    gv[nt] = n1g[c]; bv2[nt] = n1b[c];
  }
  #pragma unroll
  for (int mt = 0; mt < 4; ++mt)
    #pragma unroll
    for (int r = 0; r < 4; ++r){
      float s1 = pj[mt][0][r] + pj[mt][1][r] + pj[mt][2][r];
      float s2 = pj[mt][0][r]*pj[mt][0][r] + pj[mt][1][r]*pj[mt][1][r] + pj[mt][2][r]*pj[mt][2][r];
      #pragma unroll
      for (int mk = 1; mk < 16; mk <<= 1){ s1 += __shfl_xor(s1, mk); s2 += __shfl_xor(s2, mk); }
      if (l15 == 0){
        int t = mt*16 + kg*4 + r;
        lnred[t*8 + wave*2]     = s1;
        lnred[t*8 + wave*2 + 1] = s2;
      }
    }
  __syncthreads();
  #pragma unroll
  for (int mt = 0; mt < 4; ++mt)
    #pragma unroll 1
    for (int r = 0; r < 4; ++r){
      int t = mt*16 + kg*4 + r;
      float a1 = lnred[t*8+0] + lnred[t*8+2] + lnred[t*8+4] + lnred[t*8+6];
      float a2 = lnred[t*8+1] + lnred[t*8+3] + lnred[t*8+5] + lnred[t*8+7];
      float mu = a1 * (1.f/192.f);
      float rs = rsqrtf(a2 * (1.f/192.f) - mu*mu + LN_EPS);
      int i = t >> 3, j = t & 7;
      int h0 = ((wh<<3) + i + 4) & 255, w0 = ((ww<<3) + j + 4) & 255;
      size_t base = imgbase + (size_t)(h0*256 + w0)*192;
      #pragma unroll
      for (int nt = 0; nt < 3; ++nt){
        int c = wave*48 + nt*16 + l15;
        x1[base + c] = x[base + c] + (pj[mt][nt][r] - mu)*rs*gv[nt] + bv2[nt];
      }
    }
}

// =====================================================================
// K2 (tier0 fallback): MLP in-place on f32 xio (round-11 proven)
// =====================================================================
__global__ __launch_bounds__(256, 3) void k_mlp(
    float* xio, const u16* __restrict__ fc1_bf,
    const float* __restrict__ fc1_b, const u16* __restrict__ fc2_bf,
    const float* __restrict__ fc2_b, const float* __restrict__ n2g,
    const float* __restrict__ n2b)
{
  __shared__ __align__(16) u16 xt[64*200];
  __shared__ __align__(16) u16 hl[64*200];
  __shared__ float lnred[64*8];

  const int tid  = threadIdx.x;
  const int wave = tid >> 6, lane = tid & 63;
  const int kg   = lane >> 4, l15 = lane & 15;
  const size_t t0 = (size_t)blockIdx.x * 64;

  for (int s = tid; s < 64*96; s += 256){
    int t = s / 96, c2 = s - t*96;
    float2 v = LDF2(xio + (t0 + t)*192 + c2*2);
    ST_U32(xt + t*200 + c2*2, pack2(v.x, v.y));
  }
  f32x4 m2[4][3];
  #pragma unroll
  for (int mt = 0; mt < 4; ++mt)
    #pragma unroll
    for (int nt = 0; nt < 3; ++nt){
      float bv = fc2_b[wave*48 + nt*16 + l15];
      m2[mt][nt] = {bv, bv, bv, bv};
    }
  __syncthreads();

  f32x4 a1[4][3];
  #pragma unroll
  for (int mt = 0; mt < 4; ++mt)
    #pragma unroll
    for (int nt = 0; nt < 3; ++nt){
      float bv = fc1_b[wave*48 + nt*16 + l15];
      a1[mt][nt] = {bv, bv, bv, bv};
    }
  #pragma unroll 2
  for (int kt = 0; kt < 6; ++kt){
    bf16x8 af[4];
    #pragma unroll
    for (int mt = 0; mt < 4; ++mt)
      af[mt] = ldsfrag(xt + (mt*16 + l15)*200 + kt*32 + kg*8);
    #pragma unroll
    for (int nt = 0; nt < 3; ++nt){
      bf16x8 bfr = gfrag(fc1_bf + (size_t)(wave*48 + nt*16 + l15)*192 + kt*32 + kg*8);
      #pragma unroll
      for (int mt = 0; mt < 4; ++mt)
        a1[mt][nt] = MFMA16(af[mt], bfr, a1[mt][nt]);
    }
  }

  #pragma unroll 1
  for (int c = 0; c < 4; ++c){
    #pragma unroll
    for (int mt = 0; mt < 4; ++mt)
      #pragma unroll
      for (int nt = 0; nt < 3; ++nt)
        #pragma unroll
        for (int r = 0; r < 4; ++r)
          hl[(mt*16 + kg*4 + r)*200 + wave*48 + nt*16 + l15] = f2bf(gelu_f(a1[mt][nt][r]));
    __syncthreads();

    #pragma unroll 2
    for (int kt = 0; kt < 6; ++kt){
      bf16x8 af[4];
      #pragma unroll
      for (int mt = 0; mt < 4; ++mt)
        af[mt] = ldsfrag(hl + (mt*16 + l15)*200 + kt*32 + kg*8);
      #pragma unroll
      for (int nt = 0; nt < 3; ++nt){
        bf16x8 bfr = gfrag(fc2_bf + (size_t)(wave*48 + nt*16 + l15)*768 + c*192 + kt*32 + kg*8);
        #pragma unroll
        for (int mt = 0; mt < 4; ++mt)
          m2[mt][nt] = MFMA16(af[mt], bfr, m2[mt][nt]);
      }
    }
    if (c < 3){
      const int cn = c + 1;
      #pragma unroll
      for (int mt = 0; mt < 4; ++mt)
        #pragma unroll
        for (int nt = 0; nt < 3; ++nt){
          float bv = fc1_b[cn*192 + wave*48 + nt*16 + l15];
          a1[mt][nt] = {bv, bv, bv, bv};
        }
      #pragma unroll 2
      for (int kt = 0; kt < 6; ++kt){
        bf16x8 af[4];
        #pragma unroll
        for (int mt = 0; mt < 4; ++mt)
          af[mt] = ldsfrag(xt + (mt*16 + l15)*200 + kt*32 + kg*8);
        #pragma unroll
        for (int nt = 0; nt < 3; ++nt){
          bf16x8 bfr = gfrag(fc1_bf + (size_t)(cn*192 + wave*48 + nt*16 + l15)*192 + kt*32 + kg*8);
          #pragma unroll
          for (int mt = 0; mt < 4; ++mt)
            a1[mt][nt] = MFMA16(af[mt], bfr, a1[mt][nt]);
        }
      }
    }
    __syncthreads();
  }

  float gv[3], bv2[3];
  #pragma unroll
  for (int nt = 0; nt < 3; ++nt){
    int cc = wave*48 + nt*16 + l15;
    gv[nt] = n2g[cc]; bv2[nt] = n2b[cc];
  }
  #pragma unroll
  for (int mt = 0; mt < 4; ++mt)
    #pragma unroll
    for (int r = 0; r < 4; ++r){
      float s1 = m2[mt][0][r] + m2[mt][1][r] + m2[mt][2][r];
      float s2 = m2[mt][0][r]*m2[mt][0][r] + m2[mt][1][r]*m2[mt][1][r] + m2[mt][2][r]*m2[mt][2][r];
      #pragma unroll
      for (int mk = 1; mk < 16; mk <<= 1){ s1 += __shfl_xor(s1, mk); s2 += __shfl_xor(s2, mk); }
      if (l15 == 0){
        int t = mt*16 + kg*4 + r;
        lnred[t*8 + wave*2]     = s1;
        lnred[t*8 + wave*2 + 1] = s2;
      }
    }
  __syncthreads();
  #pragma unroll
  for (int mt = 0; mt < 4; ++mt)
    #pragma unroll 1
    for (int r = 0; r < 4; ++r){
      int t = mt*16 + kg*4 + r;
      float a1s = lnred[t*8+0] + lnred[t*8+2] + lnred[t*8+4] + lnred[t*8+6];
      float a2s = lnred[t*8+1] + lnred[t*8+3] + lnred[t*8+5] + lnred[t*8+7];
      float mu = a1s * (1.f/192.f);
      float rs = rsqrtf(a2s * (1.f/192.f) - mu*mu + LN_EPS);
      size_t base = (t0 + t)*192;
      #pragma unroll
      for (int nt = 0; nt < 3; ++nt){
        int cc = wave*48 + nt*16 + l15;
        xio[base + cc] = xio[base + cc] + (m2[mt][nt][r] - mu)*rs*gv[nt] + bv2[nt];
      }
    }
}

extern "C" void kernel_launch(void* const* d_in, const int* in_sizes, int n_in,
                              void* d_out, int out_size, void* d_ws, size_t ws_size,
                              hipStream_t stream)
{
  const float* x      = (const float*)d_in[0];
  const float* mask   = (const float*)d_in[1];
  const int*   relidx = (const int*)d_in[2];
  const float* qkv_w  = (const float*)d_in[3];
  const float* qkv_b  = (const float*)d_in[4];
  const float* proj_w = (const float*)d_in[5];
  const float* proj_b = (const float*)d_in[6];
  const float* rpb    = (const float*)d_in[7];
  const float* n1g    = (const float*)d_in[8];
  const float* n1b    = (const float*)d_in[9];
  const float* n2g    = (const float*)d_in[10];
  const float* n2b    = (const float*)d_in[11];
  const float* fc1_w  = (const float*)d_in[12];
  const float* fc1_b  = (const float*)d_in[13];
  const float* fc2_w  = (const float*)d_in[14];
  const float* fc2_b  = (const float*)d_in[15];
  float* xio = (float*)d_out;

  u16* qkv_bf  = (u16*)d_ws;
  u16* proj_bf = qkv_bf + NQKV;
  u16* fc1_bf  = proj_bf + NPRJ;
  u16* fc2_bf  = fc1_bf + NFC;
  float* rpbm  = (float*)(fc2_bf + NFC);
  float* rpbmT = rpbm + 6*4096;
  u16* Qg  = (u16*)((char*)d_ws + WS_SPLIT_HDR);
  u16* Kg  = Qg + QKV_SLAB;
  u16* VTg = Kg + QKV_SLAB;

  const int tier = (ws_size >= WS_SPLIT_NEED) ? 1 : 0;

  k_prep<<<dim3(512), dim3(256), 0, stream>>>(qkv_w, proj_w, fc1_w, fc2_w,
      rpb, relidx, qkv_bf, proj_bf, fc1_bf, fc2_bf, rpbm, rpbmT, tier);
  if (tier){
    k_qkv<<<dim3(4096), dim3(256), 0, stream>>>(x, qkv_bf, qkv_b, Qg, Kg, VTg);
    k_fused<<<dim3(4096), dim3(256), 0, stream>>>(x, mask, rpbmT, Qg, Kg, VTg,
        proj_bf, proj_b, n1g, n1b, fc1_bf, fc1_b, fc2_bf, fc2_b, n2g, n2b, xio);
  } else {
    k_attn<<<dim3(4096), dim3(256), 0, stream>>>(x, mask, rpbm, qkv_bf, qkv_b,
        proj_bf, proj_b, n1g, n1b, xio);
    k_mlp<<<dim3(4096), dim3(256), 0, stream>>>(xio, fc1_bf, fc1_b, fc2_bf, fc2_b,
        n2g, n2b);
  }
}